// Round 18
// baseline (64.279 us; speedup 1.0000x reference)
//
#include <hip/hip_runtime.h>
#include <hip/hip_bf16.h>
#include <math.h>

// SimCLR NT-Xent: B=4096, D=256, n=8192, T=0.5.
// z' = sqrt(K1) * rownorm(concat(a,b)) as bf16, row-swizzled in global:
//   stored_byte_in_row = logical_byte ^ ((row&7)<<4)
// MFMA(z', z'^T) = K1 * dot -> exp(sim) = exp2(MFMA out).  E SYMMETRIC.
// Round 18 = R16 (best, 42.25) with the MFMA shape switched to
// mfma_f32_32x32x16_bf16: halves instruction count (16/JT vs 32), higher
// pipe ceiling (2495 vs 2075 TF), two 8-deep chains (accA/accB) instead of
// two 8-deep 16x16 chains at 2x the inst count. Layout-safe: A and B use
// the IDENTICAL lane->(row,k) loader (k-permutation cancels in z z^T);
// C/D layout (col=lane&31, row=(reg&3)+8*(reg>>2)+4*(lane>>5)) is the
// HW-verified m74/m101 mapping. Cover/slots/staging/barriers = R16.
// loss = mean( ln2 * (log2(S_i - exp2(self_i)) - K1*posdot_i) ).

#define NROWS 8192
#define BHALF 4096
#define DDIM  256
#define ROWB  512                 // bytes per bf16 row
#define JT    32                  // cols per JT-tile
#define TILEB (JT * ROWB)         // 16 KiB per LDS buffer (16 slots x 1KB)
#define SSTRIDE 64                // s_part row stride (floats) = slot count

#define SQRT_K1 1.6986436f        // sqrt(2*log2(e))
#define LN2F 0.6931471805599453f

typedef __attribute__((ext_vector_type(8))) __bf16 bf16x8;
typedef __attribute__((ext_vector_type(16))) float f32x16;

#if __has_builtin(__builtin_amdgcn_exp2f)
#define FEXP2(x) __builtin_amdgcn_exp2f(x)
#else
#define FEXP2(x) __exp2f(x)
#endif
#if __has_builtin(__builtin_amdgcn_logf)
#define FLOG2(x) __builtin_amdgcn_logf(x)
#else
#define FLOG2(x) __log2f(x)
#endif

__device__ __forceinline__ float bfu(unsigned short u) {
  union { unsigned v; float f; } x; x.v = ((unsigned)u) << 16; return x.f;
}

// ---------------- Kernel 1: normalize+scale rows -> swizzled bf16 ----------
__global__ __launch_bounds__(256) void norm_kernel(
    const float* __restrict__ a, const float* __restrict__ b,
    char* __restrict__ zb, float* __restrict__ selfdot) {
  int row = blockIdx.x * 4 + (threadIdx.x >> 6);
  int lane = threadIdx.x & 63;
  const float* src = (row < BHALF) ? (a + (size_t)row * DDIM)
                                   : (b + (size_t)(row - BHALF) * DDIM);
  float4 v = ((const float4*)src)[lane];
  float ss = v.x * v.x + v.y * v.y + v.z * v.z + v.w * v.w;
  #pragma unroll
  for (int m = 1; m < 64; m <<= 1) ss += __shfl_xor(ss, m, 64);
  float inv = rsqrtf(ss);
  inv = inv * (1.5f - 0.5f * ss * inv * inv);
  float sc = inv * SQRT_K1;

  union { __hip_bfloat16 h; unsigned short u; } c0, c1, c2, c3;
  c0.h = __float2bfloat16(v.x * sc);
  c1.h = __float2bfloat16(v.y * sc);
  c2.h = __float2bfloat16(v.z * sc);
  c3.h = __float2bfloat16(v.w * sc);
  float q0 = bfu(c0.u), q1 = bfu(c1.u), q2 = bfu(c2.u), q3 = bfu(c3.u);
  float sq = q0 * q0 + q1 * q1 + q2 * q2 + q3 * q3;
  #pragma unroll
  for (int m = 1; m < 64; m <<= 1) sq += __shfl_xor(sq, m, 64);

  ushort4 o = make_ushort4(c0.u, c1.u, c2.u, c3.u);
  int off = row * ROWB + ((lane * 8) ^ ((row & 7) << 4));
  *(ushort4*)(zb + off) = o;
  if (lane == 0) selfdot[row] = sq;
}

// ---------------- Kernel 2: triangular z z^T + exp2 sums, 32x32 MFMA -------
// Grid (64, 11): t = x (128-row strip), b = y (3 squares d=3b..3b+2).
// 256 thr = 4 waves x 32 rows. 3 blocks/CU (33 KB LDS, ~150 VGPR).
__global__ __launch_bounds__(256, 3) void sim_kernel(
    const char* __restrict__ zb, float* __restrict__ s_part) {
  __shared__ __align__(16) char lds[2 * TILEB];   // 32 KiB double buffer
  __shared__ float cred[2][4][32];                // 1 KiB, parity-banked

  int t = blockIdx.x;              // 0..63
  int b = blockIdx.y;              // 0..10

  int wave = threadIdx.x >> 6;
  int lane = threadIdx.x & 63;
  int l31 = lane & 31;
  int lh  = lane >> 5;             // half-wave (k-group)
  int swz = (lane & 7) << 4;       // row/col swizzle key (row&7 == lane&7)
  int r0 = t * 128 + wave * 32;

  // --- preload A fragments: 16 x bf16x8 = 64 VGPR.
  // Frag kk: lane l -> row r0+(l&31), k-bytes kk*32 + (l>>5)*16 (16B).
  bf16x8 af[16];
  {
    const char* rp = zb + (size_t)(r0 + l31) * ROWB;
    #pragma unroll
    for (int kk = 0; kk < 16; ++kk)
      af[kk] = *(const bf16x8*)(rp + ((kk * 32 + lh * 16) ^ swz));
  }

  float sacc[16] = {};             // persistent row accumulators (reg r)
  f32x16 accA, accB;
  bf16x8 bfv[4];

  // stage slot s_ = wave*4+i: B-frag s_ of a 32-col tile, fragment order.
  // Source: col = colbase+(l&31), bytes (s_*32 + (l>>5)*16)^swz; dest linear.
  #define STAGE_SLOT(dstbuf, colbase, i) do {                                 \
    int s_ = wave * 4 + (i);                                                  \
    const char* g_ = zb + (size_t)((colbase) + l31) * ROWB +                  \
                     ((s_ * 32 + lh * 16) ^ swz);                             \
    char* l_ = lds + (dstbuf) * TILEB + s_ * 1024;                            \
    __builtin_amdgcn_global_load_lds(                                         \
        (const __attribute__((address_space(1))) void*)g_,                    \
        (__attribute__((address_space(3))) void*)l_, 16, 0, 0);               \
  } while (0)

  // chunk c: 4 frag reads (conflict-free b128), 1 stage, 4 MFMA (2 per chain)
  #define CHUNK(c) do {                                                       \
    const char* lbr = lds + buf * TILEB + lane * 16;                          \
    bfv[0] = *(const bf16x8*)(lbr + ((c) * 4 + 0) * 1024);                    \
    bfv[1] = *(const bf16x8*)(lbr + ((c) * 4 + 1) * 1024);                    \
    bfv[2] = *(const bf16x8*)(lbr + ((c) * 4 + 2) * 1024);                    \
    bfv[3] = *(const bf16x8*)(lbr + ((c) * 4 + 3) * 1024);                    \
    if (!last) STAGE_SLOT(buf ^ 1, nextbase, c);                              \
    __builtin_amdgcn_s_setprio(1);                                            \
    accA = __builtin_amdgcn_mfma_f32_32x32x16_bf16(af[(c)*4+0], bfv[0], accA, 0, 0, 0); \
    accB = __builtin_amdgcn_mfma_f32_32x32x16_bf16(af[(c)*4+1], bfv[1], accB, 0, 0, 0); \
    accA = __builtin_amdgcn_mfma_f32_32x32x16_bf16(af[(c)*4+2], bfv[2], accA, 0, 0, 0); \
    accB = __builtin_amdgcn_mfma_f32_32x32x16_bf16(af[(c)*4+3], bfv[3], accB, 0, 0, 0); \
    __builtin_amdgcn_s_setprio(0);                                            \
  } while (0)

  // colbase of JT q (q = 0..11): d = 3b + (q>>2), chunk j = q&3
  #define COLBASE(q) ((((t + 3 * b + ((q) >> 2)) & 63) << 7) + (((q) & 3) << 5))

  // prologue: stage JT 0 (4 slots per wave), drain, barrier
  {
    int cb0 = COLBASE(0);
    #pragma unroll
    for (int i = 0; i < 4; ++i) STAGE_SLOT(0, cb0, i);
  }
  asm volatile("s_waitcnt vmcnt(0)" ::: "memory");
  __builtin_amdgcn_sched_barrier(0);
  __builtin_amdgcn_s_barrier();

  for (int jt = 0; jt < 12; ++jt) {
    int buf = jt & 1;
    int d = 3 * b + (jt >> 2);
    int u = (t + d) & 63;
    bool last = (jt == 11);
    int nextbase = last ? 0 : COLBASE(jt + 1);

    accA = (f32x16)(0.f);
    accB = (f32x16)(0.f);
    CHUNK(0);
    CHUNK(1);
    CHUNK(2);
    CHUNK(3);

    // ---- flush: single exp2 on accA+accB; row + col partials ----
    bool harvest = (d >= 1) && (d <= 31);   // two-sided squares only
    {
      float cs = 0.f;
      #pragma unroll
      for (int r = 0; r < 16; ++r) {
        float e = FEXP2(accA[r] + accB[r]);
        sacc[r] += e;
        cs += e;
      }
      cs += __shfl_xor(cs, 32, 64);
      if (harvest && lane < 32) cred[jt & 1][wave][lane] = cs;
    }

    if ((jt & 3) == 3) {                    // square end: row flush, slot d
      #pragma unroll
      for (int r = 0; r < 16; ++r) {
        float v = sacc[r];
        v += __shfl_xor(v, 1, 64);
        v += __shfl_xor(v, 2, 64);
        v += __shfl_xor(v, 4, 64);
        v += __shfl_xor(v, 8, 64);
        v += __shfl_xor(v, 16, 64);
        if ((lane & 31) == 0) {
          int grow = r0 + (r & 3) + 4 * lh + 8 * (r >> 2);
          s_part[(size_t)grow * SSTRIDE + d] = v;
        }
        sacc[r] = 0.f;
      }
    }

    asm volatile("s_waitcnt vmcnt(0) lgkmcnt(0)" ::: "memory");
    __builtin_amdgcn_sched_barrier(0);
    __builtin_amdgcn_s_barrier();

    // post-barrier: one wave writes this JT's 32 col-sums (slot 32+d)
    if (harvest && wave == (jt & 3) && lane < 32) {
      int colrow = u * 128 + (jt & 3) * 32 + lane;
      float v = cred[jt & 1][0][lane] + cred[jt & 1][1][lane] +
                cred[jt & 1][2][lane] + cred[jt & 1][3][lane];
      s_part[(size_t)colrow * SSTRIDE + 32 + d] = v;
    }
  }
  #undef COLBASE
  #undef CHUNK
  #undef STAGE_SLOT
}

// ---------------- Kernel 3: per-row term (pos dot + assemble) --------------
// 512 blocks x 4 waves x 4 rows.
__global__ __launch_bounds__(256) void rowterm_kernel(
    const char* __restrict__ zb, const float* __restrict__ s_part,
    const float* __restrict__ selfdot, float* __restrict__ bpart) {
  int wave = threadIdx.x >> 6;
  int lane = threadIdx.x & 63;
  int rbase = blockIdx.x * 16 + wave * 4;
  float wacc = 0.f;
  #pragma unroll
  for (int rr = 0; rr < 4; ++rr) {
    int i = rbase + rr;
    int j = i ^ BHALF;                       // (i+B) mod 2B
    int wo = (lane * 8) ^ ((i & 7) << 4);    // j&7 == i&7 (4096 % 8 == 0)
    ushort4 zi = *(const ushort4*)(zb + (size_t)i * ROWB + wo);
    ushort4 zj = *(const ushort4*)(zb + (size_t)j * ROWB + wo);
    float dot = bfu(zi.x) * bfu(zj.x) + bfu(zi.y) * bfu(zj.y) +
                bfu(zi.z) * bfu(zj.z) + bfu(zi.w) * bfu(zj.w);
    float sp = s_part[(size_t)i * SSTRIDE + lane];   // all 64 slots, coalesced
    #pragma unroll
    for (int m = 1; m < 64; m <<= 1) {
      dot += __shfl_xor(dot, m, 64);
      sp += __shfl_xor(sp, m, 64);
    }
    float S = sp - FEXP2(selfdot[i]);          // remove diagonal
    wacc += LN2F * (FLOG2(S) - dot);           // denom - pos (2's cancel)
  }
  __shared__ float red[4];
  if (lane == 0) red[wave] = wacc;
  __syncthreads();
  if (threadIdx.x == 0)
    bpart[blockIdx.x] = red[0] + red[1] + red[2] + red[3];
}

// ---------------- Kernel 4: final sum --------------------------------------
__global__ __launch_bounds__(512) void final_kernel(
    const float* __restrict__ bpart, float* __restrict__ out) {
  int t = threadIdx.x;  // 512 threads = 8 waves
  float v = bpart[t];
  #pragma unroll
  for (int m = 1; m < 64; m <<= 1) v += __shfl_xor(v, m, 64);
  __shared__ float r2[8];
  if ((t & 63) == 0) r2[t >> 6] = v;
  __syncthreads();
  if (t == 0) {
    float s = 0.f;
    #pragma unroll
    for (int w = 0; w < 8; ++w) s += r2[w];
    out[0] = s / (float)NROWS;
  }
}

// ---------------- Launcher --------------------------------------------------
extern "C" void kernel_launch(void* const* d_in, const int* in_sizes, int n_in,
                              void* d_out, int out_size, void* d_ws, size_t ws_size,
                              hipStream_t stream) {
  const float* a = (const float*)d_in[0];
  const float* b = (const float*)d_in[1];
  float* out = (float*)d_out;
  char* ws = (char*)d_ws;

  char* zb = ws;                                            // 4 MiB
  float* selfdot = (float*)(ws + (size_t)NROWS * ROWB);     // 32 KiB
  float* s_part = selfdot + NROWS;                          // 2 MiB [8192][64]
  float* bpart = s_part + (size_t)NROWS * SSTRIDE;          // 2 KiB

  hipLaunchKernelGGL(norm_kernel, dim3(NROWS / 4), dim3(256), 0, stream,
                     a, b, zb, selfdot);
  hipLaunchKernelGGL(sim_kernel, dim3(64, 11), dim3(256), 0, stream,
                     zb, s_part);
  hipLaunchKernelGGL(rowterm_kernel, dim3(512), dim3(256), 0, stream,
                     zb, s_part, selfdot, bpart);
  hipLaunchKernelGGL(final_kernel, dim3(1), dim3(512), 0, stream, bpart, out);
}